// Round 3
// baseline (1301.296 us; speedup 1.0000x reference)
//
#include <hip/hip_runtime.h>
#include <hip/hip_bf16.h>

using f32x4  = __attribute__((ext_vector_type(4))) float;
using bf16x8 = __attribute__((ext_vector_type(8))) __bf16;

// ---------------------------------------------------------------------------
// Generic tiled GEMM: C[M,N] (+)= relu(A[M,K]) @ W[N,K]^T
//   - A, W fp32 row-major; converted to bf16 during LDS staging
//   - 128x128 tile, 4 waves, each wave a 64x64 quadrant, mfma 16x16x32 bf16
//   - LDS layout [kg][row][8] (k-outer) -> conflict-free b128 reads/writes
//   - ATOMIC=1: atomicAdd partial results (C pre-filled with bias)
//   - ATOMIC=0: epilogue adds bias, plain store (single k-chunk only)
// relu is ALWAYS applied to A during staging (all A inputs in this net are
// either raw inputs needing relu or pre-activation buffers).
// ---------------------------------------------------------------------------
template <int ATOMIC>
__global__ __launch_bounds__(256)
void gemm_kernel(const float* __restrict__ A, int lda,
                 const float* __restrict__ W, int ldw,
                 const float* __restrict__ bias,
                 float* __restrict__ C, int ldc,
                 int N, int K, int kchunk)
{
    __shared__ __bf16 As[4 * 128 * 8];   // [kg][row][8]
    __shared__ __bf16 Ws[4 * 128 * 8];

    const int t  = threadIdx.x;
    const int m0 = blockIdx.y << 7;
    const int n0 = blockIdx.x << 7;
    const int kb = blockIdx.z * kchunk;
    const int ke = min(kb + kchunk, K);

    // staging role: 2 threads per row, each covers 16 consecutive k
    const int srow = t >> 1;
    const int kh   = (t & 1) << 4;   // 0 or 16
    const int kg0  = (t & 1) << 1;   // 0 or 2

    // compute role
    const int lane = t & 63;
    const int wv   = t >> 6;
    const int wr   = (wv >> 1) << 6;   // wave row offset (0/64)
    const int wc   = (wv & 1) << 6;    // wave col offset (0/64)
    const int lr   = lane & 15;
    const int lkg  = lane >> 4;

    f32x4 acc[4][4] = {};

    const bool  wok  = (n0 + srow) < N;
    const float* Arow = A + (size_t)(m0 + srow) * lda + kh;
    const float* Wrow = W + (size_t)(wok ? (n0 + srow) : 0) * ldw + kh;

    bf16x8* Asv = reinterpret_cast<bf16x8*>(As);
    bf16x8* Wsv = reinterpret_cast<bf16x8*>(Ws);

    for (int k0 = kb; k0 < ke; k0 += 32) {
        float va[16], vw[16];
        if (k0 + 32 <= K) {
            const float4* ap = reinterpret_cast<const float4*>(Arow + k0);
#pragma unroll
            for (int i = 0; i < 4; ++i) {
                float4 f = ap[i];
                va[4*i+0] = f.x; va[4*i+1] = f.y; va[4*i+2] = f.z; va[4*i+3] = f.w;
            }
            if (wok) {
                const float4* wp = reinterpret_cast<const float4*>(Wrow + k0);
#pragma unroll
                for (int i = 0; i < 4; ++i) {
                    float4 f = wp[i];
                    vw[4*i+0] = f.x; vw[4*i+1] = f.y; vw[4*i+2] = f.z; vw[4*i+3] = f.w;
                }
            } else {
#pragma unroll
                for (int i = 0; i < 16; ++i) vw[i] = 0.f;
            }
        } else {
#pragma unroll
            for (int i = 0; i < 16; ++i) {
                int kk = k0 + kh + i;
                va[i] = (kk < K) ? Arow[k0 + i] : 0.f;
                vw[i] = (wok && kk < K) ? Wrow[k0 + i] : 0.f;
            }
        }

        bf16x8 pa0, pa1, pw0, pw1;
#pragma unroll
        for (int i = 0; i < 8; ++i) {
            pa0[i] = (__bf16)fmaxf(va[i],     0.f);
            pa1[i] = (__bf16)fmaxf(va[8 + i], 0.f);
            pw0[i] = (__bf16)vw[i];
            pw1[i] = (__bf16)vw[8 + i];
        }

        __syncthreads();   // previous iteration's reads done
        Asv[(kg0    ) * 128 + srow] = pa0;
        Asv[(kg0 + 1) * 128 + srow] = pa1;
        Wsv[(kg0    ) * 128 + srow] = pw0;
        Wsv[(kg0 + 1) * 128 + srow] = pw1;
        __syncthreads();   // writes visible

        bf16x8 af[4], wf[4];
#pragma unroll
        for (int m = 0; m < 4; ++m) af[m] = Asv[lkg * 128 + wr + m * 16 + lr];
#pragma unroll
        for (int n = 0; n < 4; ++n) wf[n] = Wsv[lkg * 128 + wc + n * 16 + lr];
#pragma unroll
        for (int m = 0; m < 4; ++m)
#pragma unroll
            for (int n = 0; n < 4; ++n)
                acc[m][n] = __builtin_amdgcn_mfma_f32_16x16x32_bf16(
                    af[m], wf[n], acc[m][n], 0, 0, 0);
    }

    // epilogue: C/D layout col = lane&15, row = (lane>>4)*4 + j
#pragma unroll
    for (int n = 0; n < 4; ++n) {
        int col = n0 + wc + n * 16 + lr;
        if (col < N) {
            float bv = ATOMIC ? 0.f : bias[col];
#pragma unroll
            for (int m = 0; m < 4; ++m) {
#pragma unroll
                for (int j = 0; j < 4; ++j) {
                    int row = m0 + wr + m * 16 + lkg * 4 + j;
                    if (ATOMIC)
                        atomicAdd(&C[(size_t)row * ldc + col], acc[m][n][j]);
                    else
                        C[(size_t)row * ldc + col] = acc[m][n][j] + bv;
                }
            }
        }
    }
}

// C[row, col] = bias[col]  for col < N  (ldc-strided)
__global__ __launch_bounds__(256)
void fill_bias(float* __restrict__ C, const float* __restrict__ bias,
               int ldc, int N)
{
    int col = blockIdx.x * 256 + threadIdx.x;
    int row = blockIdx.y;
    if (col < N) C[(size_t)row * ldc + col] = bias[col];
}

// out[b, j] = -|| relu(label_vecs[idx] - emb[b]) ||_2 ,  j=0 -> pls, j>=1 -> nls
__global__ __launch_bounds__(256)
void score_kernel(const float* __restrict__ emb,
                  const float* __restrict__ labels,
                  const int* __restrict__ pls,
                  const int* __restrict__ nls,
                  float* __restrict__ out)
{
    const int b = blockIdx.x;
    __shared__ float e[600];
    for (int i = threadIdx.x; i < 600; i += 256) e[i] = emb[(size_t)b * 600 + i];
    __syncthreads();

    const int w = threadIdx.x >> 6;
    const int lane = threadIdx.x & 63;
    for (int j = w; j < 129; j += 4) {
        int idx = (j == 0) ? pls[b] : nls[(size_t)b * 128 + (j - 1)];
        const float* lv = labels + (size_t)idx * 600;
        float s = 0.f;
        for (int d = lane; d < 600; d += 64) {
            float df = lv[d] - e[d];
            df = fmaxf(df, 0.f);
            s += df * df;
        }
#pragma unroll
        for (int off = 32; off >= 1; off >>= 1) s += __shfl_xor(s, off, 64);
        if (lane == 0) out[(size_t)b * 129 + j] = -sqrtf(s);
    }
}

extern "C" void kernel_launch(void* const* d_in, const int* in_sizes, int n_in,
                              void* d_out, int out_size, void* d_ws, size_t ws_size,
                              hipStream_t stream)
{
    const float* vfs    = (const float*)d_in[0];
    const float* labels = (const float*)d_in[1];
    const int*   pls    = (const int*)d_in[2];
    const int*   nls    = (const int*)d_in[3];
    const float* W_h1   = (const float*)d_in[4];
    const float* b_h1   = (const float*)d_in[5];
    const float* W_e1   = (const float*)d_in[6];
    const float* b_e1   = (const float*)d_in[7];
    const float* W_h2   = (const float*)d_in[8];
    const float* b_h2   = (const float*)d_in[9];
    const float* W_e2   = (const float*)d_in[10];
    const float* b_e2   = (const float*)d_in[11];
    const float* W_h    = (const float*)d_in[12];
    const float* b_h    = (const float*)d_in[13];
    const float* W_e    = (const float*)d_in[14];
    const float* b_e    = (const float*)d_in[15];

    float* ws   = (float*)d_ws;
    const size_t MB = 1u << 20;
    float* h_s  = ws;            // [1024,2048] pre-act
    float* h_o  = ws + 2 * MB;   // [1024,2048] pre-act
    float* h_p  = ws + 4 * MB;   // [1024,4096] pre-act
    float* z    = ws + 8 * MB;   // [1024,1800] pre-relu concat
    float* h2p  = ws + 10 * MB;  // [1024,1800] pre-act
    float* emb  = ws + 12 * MB;  // [1024,600]

    dim3 blk(256);
    auto kc = [](int K, int S) { int nk = (K + 31) / 32; return ((nk + S - 1) / S) * 32; };

    // bias prefills for atomic-accumulated outputs
    fill_bias<<<dim3(8, 1024), blk, 0, stream>>>(h_s,      b_h1, 2048, 2048);
    fill_bias<<<dim3(8, 1024), blk, 0, stream>>>(h_o,      b_h1, 2048, 2048);
    fill_bias<<<dim3(3, 1024), blk, 0, stream>>>(z,        b_e1, 1800, 600);
    fill_bias<<<dim3(3, 1024), blk, 0, stream>>>(z + 600,  b_e2, 1800, 600);
    fill_bias<<<dim3(3, 1024), blk, 0, stream>>>(z + 1200, b_e1, 1800, 600);
    fill_bias<<<dim3(8, 1024), blk, 0, stream>>>(h2p,      b_h,  1800, 1800);
    fill_bias<<<dim3(3, 1024), blk, 0, stream>>>(emb,      b_e,  600,  600);

    // layer-1 hidden: sbj / obj (shared W_h1), split-K=2 for occupancy
    gemm_kernel<1><<<dim3(16, 8, 2), blk, 0, stream>>>(vfs,        12288, W_h1, 4096, nullptr, h_s, 2048, 2048, 4096, kc(4096, 2));
    gemm_kernel<1><<<dim3(16, 8, 2), blk, 0, stream>>>(vfs + 8192, 12288, W_h1, 4096, nullptr, h_o, 2048, 2048, 4096, kc(4096, 2));
    // layer-1 hidden: pre (K=12288, grid already 256 blocks -> plain store)
    gemm_kernel<0><<<dim3(32, 8, 1), blk, 0, stream>>>(vfs,        12288, W_h2, 12288, b_h2,  h_p, 4096, 4096, 12288, kc(12288, 1));
    // e-layers -> z segments (N=600, split-K=4)
    gemm_kernel<1><<<dim3(5, 8, 4), blk, 0, stream>>>(h_s, 2048, W_e1, 2048, nullptr, z,        1800, 600, 2048, kc(2048, 4));
    gemm_kernel<1><<<dim3(5, 8, 4), blk, 0, stream>>>(h_p, 4096, W_e2, 4096, nullptr, z + 600,  1800, 600, 4096, kc(4096, 4));
    gemm_kernel<1><<<dim3(5, 8, 4), blk, 0, stream>>>(h_o, 2048, W_e1, 2048, nullptr, z + 1200, 1800, 600, 2048, kc(2048, 4));
    // fusion hidden: h2p = relu(z) @ W_h^T + b_h   (split-K=2)
    gemm_kernel<1><<<dim3(15, 8, 2), blk, 0, stream>>>(z,   1800, W_h, 1800, nullptr, h2p, 1800, 1800, 1800, kc(1800, 2));
    // embedding: emb = relu(h2p) @ W_e^T + b_e     (split-K=4)
    gemm_kernel<1><<<dim3(5, 8, 4), blk, 0, stream>>>(h2p, 1800, W_e, 1800, nullptr, emb, 600, 600, 1800, kc(1800, 4));

    // partial-order similarity scores
    score_kernel<<<dim3(1024), blk, 0, stream>>>(emb, labels, pls, nls, (float*)d_out);
}

// Round 5
// 1257.080 us; speedup vs baseline: 1.0352x; 1.0352x over previous
//
#include <hip/hip_runtime.h>
#include <hip/hip_bf16.h>

using f32x4  = __attribute__((ext_vector_type(4))) float;
using bf16x8 = __attribute__((ext_vector_type(8))) __bf16;

typedef const __attribute__((address_space(1))) unsigned int GU32;
typedef __attribute__((address_space(3))) unsigned int LU32;

__device__ __forceinline__ void gload_lds16(void* l, const void* g) {
    // async global->LDS, 16B per lane; LDS dst is wave-uniform base + lane*16
    __builtin_amdgcn_global_load_lds((GU32*)g, (LU32*)l, 16, 0, 0);
}

// ---------------------------------------------------------------------------
// Pure-bf16 GEMM (m97 structure): C[M,N] = A[M,K] @ W[N,K]^T + bias
//   - 128x128 tile, BK=64, 4 waves (64x64 quadrant each), mfma 16x16x32
//   - global_load_lds width16 staging, LDS [kg][row][8] k-outer (conflict-free)
//   - A-row split: rows >= msplit read at A + a2_off (fused sbj/obj stacking)
//   - C-row split: rows >= msplit store at C + c2_off (fused z segments)
//   - epilogue: +bias, optional relu, bf16 or f32 store
// ---------------------------------------------------------------------------
template <int RELU, int BF16OUT>
__global__ __launch_bounds__(256)
void gemm_bf16(const __bf16* __restrict__ A, int lda, long long a2_off, int msplit,
               const __bf16* __restrict__ Wt, int ldw, int wrows,
               const float* __restrict__ bias,
               void* __restrict__ Cout, int ldc, long long c2_off,
               int N, int K)
{
    __shared__ bf16x8 As[1024];   // slot = kg*128 + row, 16 KB
    __shared__ bf16x8 Ws[1024];

    const int t  = threadIdx.x;
    const int l  = t & 63;
    const int w  = t >> 6;
    const int m0 = blockIdx.y << 7;
    const int n0 = blockIdx.x << 7;

    const __bf16* Ab = A + ((m0 >= msplit) ? a2_off : 0);

    const __bf16* asrc[4];
    const __bf16* wsrc[4];
    int dslot[4];
#pragma unroll
    for (int it = 0; it < 4; ++it) {
        int slot = w * 256 + it * 64 + l;
        int kg   = slot >> 7;
        int row  = slot & 127;
        asrc[it] = Ab + (size_t)(m0 + row) * lda + kg * 8;
        int wrow = n0 + row; if (wrow >= wrows) wrow = wrows - 1;
        wsrc[it] = Wt + (size_t)wrow * ldw + kg * 8;
        dslot[it] = w * 256 + it * 64;
    }

    const int lr = l & 15, lkg = l >> 4;
    const int wr = (w >> 1) << 6, wc = (w & 1) << 6;

    f32x4 acc[4][4] = {};

    for (int kb = 0; kb < K; kb += 64) {
#pragma unroll
        for (int it = 0; it < 4; ++it) {
            gload_lds16(&As[dslot[it]], asrc[it]);
            gload_lds16(&Ws[dslot[it]], wsrc[it]);
            asrc[it] += 64; wsrc[it] += 64;
        }
        __syncthreads();   // drains vmcnt -> LDS tile ready
#pragma unroll
        for (int ks = 0; ks < 2; ++ks) {
            const int kgf = ks * 4 + lkg;
            bf16x8 af[4], wf[4];
#pragma unroll
            for (int m = 0; m < 4; ++m) af[m] = As[kgf * 128 + wr + m * 16 + lr];
#pragma unroll
            for (int n = 0; n < 4; ++n) wf[n] = Ws[kgf * 128 + wc + n * 16 + lr];
#pragma unroll
            for (int m = 0; m < 4; ++m)
#pragma unroll
                for (int n = 0; n < 4; ++n)
                    acc[m][n] = __builtin_amdgcn_mfma_f32_16x16x32_bf16(
                        af[m], wf[n], acc[m][n], 0, 0, 0);
        }
        __syncthreads();   // all reads done before next overwrite
    }

    // epilogue: C/D layout col = lane&15, row = (lane>>4)*4 + j  (m89-verified)
    const long long coff = (m0 >= msplit) ? c2_off : 0;
#pragma unroll
    for (int n = 0; n < 4; ++n) {
        int col = n0 + wc + n * 16 + lr;
        if (col >= N) continue;
        float bv = bias[col];
#pragma unroll
        for (int m = 0; m < 4; ++m) {
            int rbase = m0 + wr + m * 16 + lkg * 4;
#pragma unroll
            for (int j = 0; j < 4; ++j) {
                float v = acc[m][n][j] + bv;
                if (RELU) v = fmaxf(v, 0.f);
                long long idx = (long long)(rbase + j) * ldc + col + coff;
                if (BF16OUT) ((__bf16*)Cout)[idx] = (__bf16)v;
                else         ((float*)Cout)[idx]  = v;
            }
        }
    }
}

// fp32 -> bf16 (optional relu), n must be a multiple of 8
__global__ __launch_bounds__(256)
void conv_bf16(const float* __restrict__ in, __bf16* __restrict__ out,
               long long n, int relu)
{
    long long stride = (long long)gridDim.x * 256 * 8;
    for (long long i = ((long long)blockIdx.x * 256 + threadIdx.x) * 8; i < n; i += stride) {
        float4 f0 = *(const float4*)(in + i);
        float4 f1 = *(const float4*)(in + i + 4);
        float v[8] = {f0.x, f0.y, f0.z, f0.w, f1.x, f1.y, f1.z, f1.w};
        bf16x8 o;
#pragma unroll
        for (int j = 0; j < 8; ++j) {
            float x = v[j];
            if (relu) x = fmaxf(x, 0.f);
            o[j] = (__bf16)x;
        }
        *(bf16x8*)(out + i) = o;
    }
}

// fp32 [rows][cols] -> bf16 [rows][ldo], cols..ldo-1 zero-padded (cols %8==0)
__global__ __launch_bounds__(256)
void conv_pad(const float* __restrict__ in, __bf16* __restrict__ out,
              int rows, int cols, int ldo)
{
    int v8 = ldo >> 3;
    long long total = (long long)rows * v8;
    for (long long s = (long long)blockIdx.x * 256 + threadIdx.x; s < total;
         s += (long long)gridDim.x * 256) {
        int r  = (int)(s / v8);
        int c8 = ((int)(s % v8)) << 3;
        bf16x8 o;
        if (c8 + 8 <= cols) {
            const float* p = in + (size_t)r * cols + c8;
            float4 f0 = *(const float4*)p;
            float4 f1 = *(const float4*)(p + 4);
            float v[8] = {f0.x, f0.y, f0.z, f0.w, f1.x, f1.y, f1.z, f1.w};
#pragma unroll
            for (int j = 0; j < 8; ++j) o[j] = (__bf16)v[j];
        } else {
#pragma unroll
            for (int j = 0; j < 8; ++j) o[j] = (__bf16)0.f;
        }
        *(bf16x8*)(out + (size_t)r * ldo + c8) = o;
    }
}

// zero bf16 columns c0..ld-1 of a [rows][ld] buffer (keeps K-pad region safe)
__global__ __launch_bounds__(256)
void zero_cols(__bf16* __restrict__ buf, int rows, int c0, int ld)
{
    int wpad = ld - c0;
    int total = rows * wpad;
    for (int i = blockIdx.x * 256 + threadIdx.x; i < total; i += gridDim.x * 256)
        buf[(size_t)(i / wpad) * ld + c0 + (i % wpad)] = (__bf16)0.f;
}

// out[b, j] = -|| relu(label_vecs[idx] - emb[b]) ||_2, j=0 -> pls, j>=1 -> nls
__global__ __launch_bounds__(256)
void score_kernel(const float* __restrict__ emb,
                  const float* __restrict__ labels,
                  const int* __restrict__ pls,
                  const int* __restrict__ nls,
                  float* __restrict__ out)
{
    const int b = blockIdx.x;
    __shared__ float e[600];
    for (int i = threadIdx.x; i < 600; i += 256) e[i] = emb[(size_t)b * 600 + i];
    __syncthreads();

    const int w = threadIdx.x >> 6;
    const int lane = threadIdx.x & 63;
    for (int j = w; j < 129; j += 4) {
        int idx = (j == 0) ? pls[b] : nls[(size_t)b * 128 + (j - 1)];
        const float* lv = labels + (size_t)idx * 600;
        float s = 0.f;
        for (int d = lane; d < 600; d += 64) {
            float df = lv[d] - e[d];
            df = fmaxf(df, 0.f);
            s += df * df;
        }
#pragma unroll
        for (int off = 32; off >= 1; off >>= 1) s += __shfl_xor(s, off, 64);
        if (lane == 0) out[(size_t)b * 129 + j] = -sqrtf(s);
    }
}

extern "C" void kernel_launch(void* const* d_in, const int* in_sizes, int n_in,
                              void* d_out, int out_size, void* d_ws, size_t ws_size,
                              hipStream_t stream)
{
    const float* vfs    = (const float*)d_in[0];
    const float* labels = (const float*)d_in[1];
    const int*   pls    = (const int*)d_in[2];
    const int*   nls    = (const int*)d_in[3];
    const float* W_h1   = (const float*)d_in[4];
    const float* b_h1   = (const float*)d_in[5];
    const float* W_e1   = (const float*)d_in[6];
    const float* b_e1   = (const float*)d_in[7];
    const float* W_h2   = (const float*)d_in[8];
    const float* b_h2   = (const float*)d_in[9];
    const float* W_e2   = (const float*)d_in[10];
    const float* b_e2   = (const float*)d_in[11];
    const float* W_h    = (const float*)d_in[12];
    const float* b_h    = (const float*)d_in[13];
    const float* W_e    = (const float*)d_in[14];
    const float* b_e    = (const float*)d_in[15];

    // ---- workspace layout (bytes) -------------------------------------
    char* p = (char*)d_ws;
    auto alloc = [&](size_t bytes) { char* r = p; p += (bytes + 255) & ~size_t(255); return r; };
    __bf16* vfs_bf = (__bf16*)alloc(1024ll * 12288 * 2);   // relu(vfs) bf16
    __bf16* h1     = (__bf16*)alloc(2048ll * 2048 * 2);    // relu(h) sbj|obj stacked
    __bf16* hp     = (__bf16*)alloc(1024ll * 4096 * 2);    // relu(h) pre
    __bf16* z      = (__bf16*)alloc(1024ll * 1856 * 2);    // relu(concat) K-padded
    __bf16* h2     = (__bf16*)alloc(1024ll * 1856 * 2);    // relu(h2) K-padded
    float*  emb    = (float*)alloc(1024ll * 600 * 4);
    __bf16* Wh1b   = (__bf16*)alloc(2048ll * 4096 * 2);
    __bf16* Wh2b   = (__bf16*)alloc(4096ll * 12288 * 2);
    __bf16* We1b   = (__bf16*)alloc(600ll * 2048 * 2);
    __bf16* We2b   = (__bf16*)alloc(600ll * 4096 * 2);
    __bf16* Whb    = (__bf16*)alloc(1800ll * 1856 * 2);    // zero-padded K
    __bf16* Web    = (__bf16*)alloc(600ll * 1856 * 2);     // zero-padded K

    dim3 blk(256);
    const int HUGE_SPLIT = 1 << 30;

    // ---- conversions (memory-bound) -----------------------------------
    conv_bf16<<<2048, blk, 0, stream>>>(vfs, vfs_bf, 1024ll * 12288, 1);
    conv_bf16<<<1024, blk, 0, stream>>>(W_h1, Wh1b, 2048ll * 4096, 0);
    conv_bf16<<<2048, blk, 0, stream>>>(W_h2, Wh2b, 4096ll * 12288, 0);
    conv_bf16<<<512,  blk, 0, stream>>>(W_e1, We1b, 600ll * 2048, 0);
    conv_bf16<<<512,  blk, 0, stream>>>(W_e2, We2b, 600ll * 4096, 0);
    conv_pad<<<1024, blk, 0, stream>>>(W_h, Whb, 1800, 1800, 1856);
    conv_pad<<<512,  blk, 0, stream>>>(W_e, Web, 600, 1800, 1856);
    zero_cols<<<256, blk, 0, stream>>>(z,  1024, 1800, 1856);
    zero_cols<<<256, blk, 0, stream>>>(h2, 1024, 1800, 1856);

    // ---- GEMM chain ---------------------------------------------------
    // 1) layer-1 hidden, sbj+obj fused: M=2048 (rows>=1024 read obj slice)
    gemm_bf16<1, 1><<<dim3(16, 16), blk, 0, stream>>>(
        vfs_bf, 12288, 8192ll - 1024ll * 12288, 1024,
        Wh1b, 4096, 2048, b_h1, h1, 2048, 0, 2048, 4096);
    // 2) layer-1 hidden, pre: M=1024, N=4096, K=12288
    gemm_bf16<1, 1><<<dim3(32, 8), blk, 0, stream>>>(
        vfs_bf, 12288, 0, HUGE_SPLIT,
        Wh2b, 12288, 4096, b_h2, hp, 4096, 0, 4096, 12288);
    // 3) e-layer sbj+obj fused -> z cols [0,600) and [1200,1800)
    gemm_bf16<1, 1><<<dim3(5, 16), blk, 0, stream>>>(
        h1, 2048, 0, 1024,
        We1b, 2048, 600, b_e1, z, 1856, 1200ll - 1024ll * 1856, 600, 2048);
    // 4) e-layer pre -> z cols [600,1200)
    gemm_bf16<1, 1><<<dim3(5, 8), blk, 0, stream>>>(
        hp, 4096, 0, HUGE_SPLIT,
        We2b, 4096, 600, b_e2, z + 600, 1856, 0, 600, 4096);
    // 5) fusion hidden: h2 = relu(z @ W_h^T + b_h), K padded to 1856
    gemm_bf16<1, 1><<<dim3(15, 8), blk, 0, stream>>>(
        z, 1856, 0, HUGE_SPLIT,
        Whb, 1856, 1800, b_h, h2, 1856, 0, 1800, 1856);
    // 6) embedding: emb = h2 @ W_e^T + b_e (no relu, fp32 out)
    gemm_bf16<0, 0><<<dim3(5, 8), blk, 0, stream>>>(
        h2, 1856, 0, HUGE_SPLIT,
        Web, 1856, 600, b_e, emb, 600, 0, 600, 1856);

    // ---- scores -------------------------------------------------------
    score_kernel<<<dim3(1024), blk, 0, stream>>>(emb, labels, pls, nls, (float*)d_out);
}

// Round 7
// 936.247 us; speedup vs baseline: 1.3899x; 1.3427x over previous
//
#include <hip/hip_runtime.h>
#include <hip/hip_bf16.h>

using f32x4  = __attribute__((ext_vector_type(4))) float;
using bf16x8 = __attribute__((ext_vector_type(8))) __bf16;

typedef const __attribute__((address_space(1))) unsigned int GU32;
typedef __attribute__((address_space(3))) unsigned int LU32;

__device__ __forceinline__ void gload_lds16(void* l, const void* g) {
    __builtin_amdgcn_global_load_lds((GU32*)g, (LU32*)l, 16, 0, 0);
}

// ---------------------------------------------------------------------------
// Pure-bf16 GEMM (m97 structure): C[M,N] = A[M,K] @ W[N,K]^T (+bias)
//   128x128 tile, BK=64, 4 waves, mfma 16x16x32, global_load_lds width16,
//   LDS [kg][row][8] k-outer (conflict-free b128).
//   blockIdx.z = K-chunk (split-K). PARTIAL=1: raw fp32 partial store to
//   arena (c2_off reused as z-stride), no bias. PARTIAL=0: bias+act+store.
//   msplit/a2_off: rows >= msplit read A at +a2_off (fused sbj/obj stacking).
// ---------------------------------------------------------------------------
template <int RELU, int BF16OUT, int PARTIAL>
__global__ __launch_bounds__(256)
void gemm_bf16(const __bf16* __restrict__ A, int lda, long long a2_off, int msplit,
               const __bf16* __restrict__ Wt, int ldw, int wrows,
               const float* __restrict__ bias,
               void* __restrict__ Cout, int ldc, long long c2_off,
               int N, int K, int kchunk)
{
    __shared__ bf16x8 As[1024];   // 16 KB
    __shared__ bf16x8 Ws[1024];

    const int t  = threadIdx.x;
    const int l  = t & 63;
    const int w  = t >> 6;
    const int m0 = blockIdx.y << 7;
    const int n0 = blockIdx.x << 7;
    const int kb0 = blockIdx.z * kchunk;
    const int ke  = min(kb0 + kchunk, K);

    const __bf16* Ab = A + ((m0 >= msplit) ? a2_off : 0);

    const __bf16* asrc[4];
    const __bf16* wsrc[4];
    int dslot[4];
#pragma unroll
    for (int it = 0; it < 4; ++it) {
        int slot = w * 256 + it * 64 + l;
        int kg   = slot >> 7;
        int row  = slot & 127;
        asrc[it] = Ab + (size_t)(m0 + row) * lda + kg * 8 + kb0;
        int wrow = n0 + row; if (wrow >= wrows) wrow = wrows - 1;
        wsrc[it] = Wt + (size_t)wrow * ldw + kg * 8 + kb0;
        dslot[it] = w * 256 + it * 64;
    }

    const int lr = l & 15, lkg = l >> 4;
    const int wr = (w >> 1) << 6, wc = (w & 1) << 6;

    f32x4 acc[4][4] = {};

    for (int kb = kb0; kb < ke; kb += 64) {
#pragma unroll
        for (int it = 0; it < 4; ++it) {
            gload_lds16(&As[dslot[it]], asrc[it]);
            gload_lds16(&Ws[dslot[it]], wsrc[it]);
            asrc[it] += 64; wsrc[it] += 64;
        }
        __syncthreads();
#pragma unroll
        for (int ks = 0; ks < 2; ++ks) {
            const int kgf = ks * 4 + lkg;
            bf16x8 af[4], wf[4];
#pragma unroll
            for (int m = 0; m < 4; ++m) af[m] = As[kgf * 128 + wr + m * 16 + lr];
#pragma unroll
            for (int n = 0; n < 4; ++n) wf[n] = Ws[kgf * 128 + wc + n * 16 + lr];
#pragma unroll
            for (int m = 0; m < 4; ++m)
#pragma unroll
                for (int n = 0; n < 4; ++n)
                    acc[m][n] = __builtin_amdgcn_mfma_f32_16x16x32_bf16(
                        af[m], wf[n], acc[m][n], 0, 0, 0);
        }
        __syncthreads();
    }

    // epilogue: C/D layout col = lane&15, row = (lane>>4)*4 + j (m89-verified)
    const long long coff = PARTIAL ? (long long)blockIdx.z * c2_off
                                   : ((m0 >= msplit) ? c2_off : 0);
#pragma unroll
    for (int n = 0; n < 4; ++n) {
        int col = n0 + wc + n * 16 + lr;
        if (col >= N) continue;
        float bv = PARTIAL ? 0.f : bias[col];
#pragma unroll
        for (int m = 0; m < 4; ++m) {
            int rbase = m0 + wr + m * 16 + lkg * 4;
#pragma unroll
            for (int j = 0; j < 4; ++j) {
                long long idx = (long long)(rbase + j) * ldc + col + coff;
                if (PARTIAL) {
                    ((float*)Cout)[idx] = acc[m][n][j];
                } else {
                    float v = acc[m][n][j] + bv;
                    if (RELU) v = fmaxf(v, 0.f);
                    if (BF16OUT) ((__bf16*)Cout)[idx] = (__bf16)v;
                    else         ((float*)Cout)[idx]  = v;
                }
            }
        }
    }
}

// out = act(sum_s part[s] + bias), 8 cols per thread; row>=msplit stores at +c2
template <int RELU, int BF16OUT>
__global__ __launch_bounds__(256)
void reduce_k(const float* __restrict__ part, long long zs, int S,
              const float* __restrict__ bias, void* __restrict__ out,
              int N, int ldc, int msplit, long long c2, int M)
{
    const int n8 = N >> 3;
    const long long total = (long long)M * n8;
    for (long long i = (long long)blockIdx.x * 256 + threadIdx.x; i < total;
         i += (long long)gridDim.x * 256) {
        int row = (int)(i / n8);
        int c8  = (int)(i - (long long)row * n8) << 3;
        long long base = (long long)row * N + c8;
        float4 s0 = {0.f, 0.f, 0.f, 0.f}, s1 = {0.f, 0.f, 0.f, 0.f};
        for (int s = 0; s < S; ++s) {
            const float4* p = (const float4*)(part + s * zs + base);
            float4 a = p[0], b = p[1];
            s0.x += a.x; s0.y += a.y; s0.z += a.z; s0.w += a.w;
            s1.x += b.x; s1.y += b.y; s1.z += b.z; s1.w += b.w;
        }
        float v[8] = {s0.x, s0.y, s0.z, s0.w, s1.x, s1.y, s1.z, s1.w};
        long long ob = (long long)row * ldc + c8 + ((row >= msplit) ? c2 : 0);
        if (BF16OUT) {
            bf16x8 o;
#pragma unroll
            for (int j = 0; j < 8; ++j) {
                float x = v[j] + bias[c8 + j];
                if (RELU) x = fmaxf(x, 0.f);
                o[j] = (__bf16)x;
            }
            *(bf16x8*)((__bf16*)out + ob) = o;
        } else {
            float4 o0, o1;
            float t0[8];
#pragma unroll
            for (int j = 0; j < 8; ++j) {
                float x = v[j] + bias[c8 + j];
                if (RELU) x = fmaxf(x, 0.f);
                t0[j] = x;
            }
            o0 = {t0[0], t0[1], t0[2], t0[3]};
            o1 = {t0[4], t0[5], t0[6], t0[7]};
            *(float4*)((float*)out + ob)     = o0;
            *(float4*)((float*)out + ob + 4) = o1;
        }
    }
}

// fp32 -> bf16 (optional relu), n multiple of 8
__global__ __launch_bounds__(256)
void conv_bf16(const float* __restrict__ in, __bf16* __restrict__ out,
               long long n, int relu)
{
    long long stride = (long long)gridDim.x * 256 * 8;
    for (long long i = ((long long)blockIdx.x * 256 + threadIdx.x) * 8; i < n; i += stride) {
        float4 f0 = *(const float4*)(in + i);
        float4 f1 = *(const float4*)(in + i + 4);
        float v[8] = {f0.x, f0.y, f0.z, f0.w, f1.x, f1.y, f1.z, f1.w};
        bf16x8 o;
#pragma unroll
        for (int j = 0; j < 8; ++j) {
            float x = v[j];
            if (relu) x = fmaxf(x, 0.f);
            o[j] = (__bf16)x;
        }
        *(bf16x8*)(out + i) = o;
    }
}

// fp32 [rows][cols] -> bf16 [rows][ldo], zero-padded cols..ldo-1
__global__ __launch_bounds__(256)
void conv_pad(const float* __restrict__ in, __bf16* __restrict__ out,
              int rows, int cols, int ldo)
{
    int v8 = ldo >> 3;
    long long total = (long long)rows * v8;
    for (long long s = (long long)blockIdx.x * 256 + threadIdx.x; s < total;
         s += (long long)gridDim.x * 256) {
        int r  = (int)(s / v8);
        int c8 = ((int)(s % v8)) << 3;
        bf16x8 o;
        if (c8 + 8 <= cols) {
            const float* p = in + (size_t)r * cols + c8;
            float4 f0 = *(const float4*)p;
            float4 f1 = *(const float4*)(p + 4);
            float v[8] = {f0.x, f0.y, f0.z, f0.w, f1.x, f1.y, f1.z, f1.w};
#pragma unroll
            for (int j = 0; j < 8; ++j) o[j] = (__bf16)v[j];
        } else {
#pragma unroll
            for (int j = 0; j < 8; ++j) o[j] = (__bf16)0.f;
        }
        *(bf16x8*)(out + (size_t)r * ldo + c8) = o;
    }
}

__global__ __launch_bounds__(256)
void zero_cols(__bf16* __restrict__ buf, int rows, int c0, int ld)
{
    int wpad = ld - c0;
    int total = rows * wpad;
    for (int i = blockIdx.x * 256 + threadIdx.x; i < total; i += gridDim.x * 256)
        buf[(size_t)(i / wpad) * ld + c0 + (i % wpad)] = (__bf16)0.f;
}

__global__ __launch_bounds__(256)
void score_kernel(const float* __restrict__ emb,
                  const float* __restrict__ labels,
                  const int* __restrict__ pls,
                  const int* __restrict__ nls,
                  float* __restrict__ out)
{
    const int b = blockIdx.x;
    __shared__ float e[600];
    for (int i = threadIdx.x; i < 600; i += 256) e[i] = emb[(size_t)b * 600 + i];
    __syncthreads();

    const int w = threadIdx.x >> 6;
    const int lane = threadIdx.x & 63;
    for (int j = w; j < 129; j += 4) {
        int idx = (j == 0) ? pls[b] : nls[(size_t)b * 128 + (j - 1)];
        const float* lv = labels + (size_t)idx * 600;
        float s = 0.f;
        for (int d = lane; d < 600; d += 64) {
            float df = lv[d] - e[d];
            df = fmaxf(df, 0.f);
            s += df * df;
        }
#pragma unroll
        for (int off = 32; off >= 1; off >>= 1) s += __shfl_xor(s, off, 64);
        if (lane == 0) out[(size_t)b * 129 + j] = -sqrtf(s);
    }
}

extern "C" void kernel_launch(void* const* d_in, const int* in_sizes, int n_in,
                              void* d_out, int out_size, void* d_ws, size_t ws_size,
                              hipStream_t stream)
{
    const float* vfs    = (const float*)d_in[0];
    const float* labels = (const float*)d_in[1];
    const int*   pls    = (const int*)d_in[2];
    const int*   nls    = (const int*)d_in[3];
    const float* W_h1   = (const float*)d_in[4];
    const float* b_h1   = (const float*)d_in[5];
    const float* W_e1   = (const float*)d_in[6];
    const float* b_e1   = (const float*)d_in[7];
    const float* W_h2   = (const float*)d_in[8];
    const float* b_h2   = (const float*)d_in[9];
    const float* W_e2   = (const float*)d_in[10];
    const float* b_e2   = (const float*)d_in[11];
    const float* W_h    = (const float*)d_in[12];
    const float* b_h    = (const float*)d_in[13];
    const float* W_e    = (const float*)d_in[14];
    const float* b_e    = (const float*)d_in[15];

    char* p = (char*)d_ws;
    auto alloc = [&](size_t bytes) { char* r = p; p += (bytes + 255) & ~size_t(255); return r; };
    __bf16* vfs_bf = (__bf16*)alloc(1024ll * 12288 * 2);
    __bf16* h1     = (__bf16*)alloc(2048ll * 2048 * 2);
    __bf16* hp     = (__bf16*)alloc(1024ll * 4096 * 2);
    __bf16* z      = (__bf16*)alloc(1024ll * 1856 * 2);
    __bf16* h2     = (__bf16*)alloc(1024ll * 1856 * 2);
    float*  emb    = (float*)alloc(1024ll * 600 * 4);
    __bf16* Wh1b   = (__bf16*)alloc(2048ll * 4096 * 2);
    __bf16* Wh2b   = (__bf16*)alloc(4096ll * 12288 * 2);
    __bf16* We1b   = (__bf16*)alloc(600ll * 2048 * 2);
    __bf16* We2b   = (__bf16*)alloc(600ll * 4096 * 2);
    __bf16* Whb    = (__bf16*)alloc(1800ll * 1856 * 2);
    __bf16* Web    = (__bf16*)alloc(600ll * 1856 * 2);

    // split-K partial arena: whatever scratch remains, capped at 64 MB.
    size_t used  = (size_t)(p - (char*)d_ws);
    size_t rem   = (ws_size > used) ? (ws_size - used) : 0;
    size_t arena = rem > (64u << 20) ? (64u << 20) : (rem & ~size_t(255));
    float* part  = (float*)alloc(arena);

    dim3 blk(256);
    const int HUGE_SPLIT = 1 << 30;

    // pick largest split S with partial fp32 buffer fitting the arena
    auto pickS = [&](int M, int N, int smax) {
        int s = smax;
        while (s > 1 && (long long)s * M * N * 4 > (long long)arena) s >>= 1;
        return s;
    };
    // generic launcher: S>1 -> partial+reduce, S==1 -> direct epilogue
    auto gemm = [&](const __bf16* A, int lda, long long a2, int msA,
                    const __bf16* W, int ldw, int wrows, const float* bias,
                    void* out, int ldc, int msC, long long c2,
                    int M, int N, int K, int relu, int bf16out, int smax) {
        int S = pickS(M, N, smax);
        int nx = (N + 127) >> 7, ny = M >> 7;
        if (S == 1) {
            if (bf16out)
                gemm_bf16<1, 1, 0><<<dim3(nx, ny, 1), blk, 0, stream>>>(
                    A, lda, a2, (msA == HUGE_SPLIT ? msC : msA), W, ldw, wrows,
                    bias, out, ldc, c2, N, K, K);
            else
                gemm_bf16<0, 0, 0><<<dim3(nx, ny, 1), blk, 0, stream>>>(
                    A, lda, a2, (msA == HUGE_SPLIT ? msC : msA), W, ldw, wrows,
                    bias, out, ldc, c2, N, K, K);
        } else {
            int kchunk = (((K + S - 1) / S) + 63) & ~63;
            long long zs = (long long)M * N;
            gemm_bf16<0, 0, 1><<<dim3(nx, ny, S), blk, 0, stream>>>(
                A, lda, a2, msA, W, ldw, wrows, nullptr,
                part, N, zs, N, K, kchunk);
            long long tot8 = (long long)M * (N >> 3);
            int rblocks = (int)((tot8 + 255) / 256);
            if (rblocks > 2048) rblocks = 2048;
            if (bf16out)
                reduce_k<1, 1><<<dim3(rblocks), blk, 0, stream>>>(
                    part, zs, S, bias, out, N, ldc, msC, c2, M);
            else
                reduce_k<0, 0><<<dim3(rblocks), blk, 0, stream>>>(
                    part, zs, S, bias, out, N, ldc, msC, c2, M);
        }
    };

    // ---- conversions --------------------------------------------------
    conv_bf16<<<2048, blk, 0, stream>>>(vfs, vfs_bf, 1024ll * 12288, 1);
    conv_bf16<<<1024, blk, 0, stream>>>(W_h1, Wh1b, 2048ll * 4096, 0);
    conv_bf16<<<2048, blk, 0, stream>>>(W_h2, Wh2b, 4096ll * 12288, 0);
    conv_bf16<<<512,  blk, 0, stream>>>(W_e1, We1b, 600ll * 2048, 0);
    conv_bf16<<<512,  blk, 0, stream>>>(W_e2, We2b, 600ll * 4096, 0);
    conv_pad<<<1024, blk, 0, stream>>>(W_h, Whb, 1800, 1800, 1856);
    conv_pad<<<512,  blk, 0, stream>>>(W_e, Web, 600, 1800, 1856);
    zero_cols<<<256, blk, 0, stream>>>(z,  1024, 1800, 1856);
    zero_cols<<<256, blk, 0, stream>>>(h2, 1024, 1800, 1856);

    // ---- GEMM chain (split-K for occupancy) ---------------------------
    // 1) layer-1 hidden, sbj+obj fused: M=2048, K=4096, S=4 -> 1024 blocks
    gemm(vfs_bf, 12288, 8192ll - 1024ll * 12288, 1024,
         Wh1b, 4096, 2048, b_h1, h1, 2048, HUGE_SPLIT, 0,
         2048, 2048, 4096, 1, 1, 4);
    // 2) layer-1 hidden, pre: M=1024, N=4096, K=12288, S=4 -> 1024 blocks
    gemm(vfs_bf, 12288, 0, HUGE_SPLIT,
         Wh2b, 12288, 4096, b_h2, hp, 4096, HUGE_SPLIT, 0,
         1024, 4096, 12288, 1, 1, 4);
    // 3) e-layer sbj+obj -> z cols [0,600)+[1200,1800): S=8 -> 640 blocks
    gemm(h1, 2048, 0, HUGE_SPLIT,
         We1b, 2048, 600, b_e1, z, 1856, 1024, 1200ll - 1024ll * 1856,
         2048, 600, 2048, 1, 1, 8);
    // 4) e-layer pre -> z cols [600,1200): S=8 -> 320 blocks
    gemm(hp, 4096, 0, HUGE_SPLIT,
         We2b, 4096, 600, b_e2, z + 600, 1856, HUGE_SPLIT, 0,
         1024, 600, 4096, 1, 1, 8);
    // 5) fusion hidden: K=1856(padded), S=4 -> 480 blocks
    gemm(z, 1856, 0, HUGE_SPLIT,
         Whb, 1856, 1800, b_h, h2, 1856, HUGE_SPLIT, 0,
         1024, 1800, 1856, 1, 1, 4);
    // 6) embedding: fp32 out, no relu, S=8 -> 320 blocks
    gemm(h2, 1856, 0, HUGE_SPLIT,
         Web, 1856, 600, b_e, emb, 600, HUGE_SPLIT, 0,
         1024, 600, 1856, 0, 0, 8);

    // ---- scores -------------------------------------------------------
    score_kernel<<<dim3(1024), blk, 0, stream>>>(emb, labels, pls, nls, (float*)d_out);
}